// Round 12
// baseline (258.054 us; speedup 1.0000x reference)
//
#include <hip/hip_runtime.h>
#include <hip/hip_bf16.h>

// ---------------------------------------------------------------------------
// Encoder3: 3-layer GCN + JK-cat + mean-pool + projection head + L2 normalize
//   - CSR build: direct bucketed fill (+fused wconv tail) + per-bucket sort.
//   - Residual stream fp32; gathered message buffers (hwbA/hwbB, ping-pong)
//     bf16 + zero sentinel row N each.
//   - gemm_in: x->h->hwbA fused (LDS round-trip).
//   - conv1/conv2: agg+gemm FUSED (32 nodes/block: gather phase -> r rows to
//     global + hi/lo planes to LDS -> MFMA phase -> hwb_next). Ping-pong
//     buffers avoid read/write race.
//   - conv3: plain agg. Pool + head fused.
// Requires N < 65536 (16-bit packing) and NB <= 512.
// ---------------------------------------------------------------------------

#define THREADS 256
#define BCAP 4096

typedef __attribute__((ext_vector_type(8))) short short8;   // 8 bf16
typedef __attribute__((ext_vector_type(4))) float f32x4;

static __device__ __forceinline__ unsigned short f2bf(float f) {
  unsigned u = __float_as_uint(f);
  u += 0x7fffu + ((u >> 16) & 1u);   // RNE
  return (unsigned short)(u >> 16);
}
static __device__ __forceinline__ float bfval(unsigned short h) {
  return __uint_as_float((unsigned)h << 16);
}
static __device__ __forceinline__ float bf_lo(unsigned w) {
  return __uint_as_float(w << 16);
}
static __device__ __forceinline__ float bf_hi(unsigned w) {
  return __uint_as_float(w & 0xffff0000u);
}

// ---- CSR build (+fused wconv) ----------------------------------------------

__global__ __launch_bounds__(THREADS) void bucket_fill_kernel(
    const int* __restrict__ src, const int* __restrict__ dst,
    int* __restrict__ bkt_cursor, unsigned* __restrict__ edges_tmp, int E,
    const float* __restrict__ W0, const float* __restrict__ W1,
    const float* __restrict__ W2, const float* __restrict__ W3,
    unsigned short* __restrict__ Wtb) {
  __shared__ int hist[512];
  __shared__ int excl[512];
  __shared__ int gbase[512];
  __shared__ unsigned staging[2048];
  int t = threadIdx.x;
  int base = blockIdx.x * 2048;
  if (base >= E) {
    int cb = (E + 2047) >> 11;
    int tid = (blockIdx.x - cb) * THREADS + t;
    if (tid < 4 * 128 * 128) {
      int w = tid >> 14, c = (tid >> 7) & 127, k = tid & 127;
      const float* W = (w == 0) ? W0 : (w == 1) ? W1 : (w == 2) ? W2 : W3;
      float f = W[k * 128 + c];
      unsigned short hi = f2bf(f);
      unsigned short lo = f2bf(f - bfval(hi));
      int c16 = c >> 4, lc = c & 15;
      int ks = k >> 5, hq = (k >> 3) & 3, j = k & 7;
      int lane = hq * 16 + lc;
      size_t wb = (size_t)w * 32768;
      size_t fidx = (size_t)((c16 * 4 + ks) * 64 + lane) * 8 + j;
      Wtb[wb + fidx] = hi;
      Wtb[wb + 16384 + fidx] = lo;
    }
    return;
  }
  hist[t] = 0; hist[t + 256] = 0;
  __syncthreads();
  int e0 = base + t * 8;
  int ds[8], ss[8];
  if (e0 + 7 < E) {
    *(int4*)&ds[0] = *(const int4*)&dst[e0];
    *(int4*)&ds[4] = *(const int4*)&dst[e0 + 4];
    *(int4*)&ss[0] = *(const int4*)&src[e0];
    *(int4*)&ss[4] = *(const int4*)&src[e0 + 4];
  } else {
#pragma unroll
    for (int k = 0; k < 8; ++k) {
      ds[k] = (e0 + k < E) ? dst[e0 + k] : -1;
      ss[k] = (e0 + k < E) ? src[e0 + k] : 0;
    }
  }
  unsigned rec[8]; int bk[8]; int slot[8];
#pragma unroll
  for (int k = 0; k < 8; ++k) {
    bk[k] = -1;
    if (ds[k] >= 0) {
      rec[k] = ((unsigned)ds[k] << 16) | (unsigned)ss[k];
      bk[k] = ds[k] >> 7;
      slot[k] = atomicAdd(&hist[bk[k]], 1);
    }
  }
  __syncthreads();
  int v0 = hist[t], v1 = hist[t + 256];
  excl[t] = v0; excl[t + 256] = v1;
  __syncthreads();
  for (int off = 1; off < 512; off <<= 1) {
    int a = (t >= off) ? excl[t - off] : 0;
    int b = excl[t + 256 - off];
    __syncthreads();
    excl[t] += a; excl[t + 256] += b;
    __syncthreads();
  }
  int e0x = excl[t] - v0, e1x = excl[t + 256] - v1;
  __syncthreads();
  excl[t] = e0x; excl[t + 256] = e1x;
  __syncthreads();
#pragma unroll
  for (int k = 0; k < 8; ++k)
    if (bk[k] >= 0) staging[excl[bk[k]] + slot[k]] = rec[k];
  if (v0) gbase[t] = atomicAdd(&bkt_cursor[t], v0);
  if (v1) gbase[t + 256] = atomicAdd(&bkt_cursor[t + 256], v1);
  __syncthreads();
  int total = (base + 2048 <= E) ? 2048 : (E - base);
  for (int p = t; p < total; p += 256) {
    unsigned r = staging[p];
    int b = (int)(r >> 23);
    int pos = gbase[b] + (p - excl[b]);
    if (pos < BCAP)
      edges_tmp[(size_t)b * BCAP + pos] = r;
  }
}

__global__ __launch_bounds__(THREADS) void node_sort_kernel(
    const unsigned* __restrict__ edges_tmp, const int* __restrict__ bkt_cursor,
    const int* __restrict__ batch, int* __restrict__ row_beg,
    int* __restrict__ deg, float* __restrict__ dis,
    int* __restrict__ csr_src, int* __restrict__ g_off,
    unsigned* __restrict__ hwbA_w, unsigned* __restrict__ hwbB_w,
    int N, int G) {
  __shared__ int lhist[128];
  __shared__ int lbase[128];
  __shared__ int lcur[128];
  int b = blockIdx.x, t = threadIdx.x;
  if (b == 0 && t >= 128 && t < 192) {
    hwbA_w[(size_t)N * 64 + (t - 128)] = 0;   // sentinel zero rows (256 B)
    hwbB_w[(size_t)N * 64 + (t - 128)] = 0;
  }
  int cnt = bkt_cursor[b];
  if (cnt > BCAP) cnt = BCAP;
  size_t ebase = (size_t)b * BCAP;
  if (t < 128) lhist[t] = 0;
  __syncthreads();
  for (int p = t; p < cnt; p += 256)
    atomicAdd(&lhist[(edges_tmp[ebase + p] >> 16) & 127], 1);
  __syncthreads();
  int pad = 0;
  if (t < 128) {
    pad = (lhist[t] + 3) & ~3;
    lbase[t] = pad;
  }
  __syncthreads();
  for (int off = 1; off < 128; off <<= 1) {
    int a = (t >= off && t < 128) ? lbase[t - off] : 0;
    __syncthreads();
    if (t < 128) lbase[t] += a;
    __syncthreads();
  }
  if (t < 128) {
    int excl = lbase[t] - pad;
    int node = b * 128 + t;
    if (node < N) {
      row_beg[node] = (int)ebase + excl;
      deg[node] = lhist[t];
      dis[node] = rsqrtf((float)lhist[t] + 1.0f);
      for (int q = lhist[t]; q < pad; ++q)
        csr_src[ebase + excl + q] = N;
      int b0 = batch[node];
      int prev = (node == 0) ? -1 : batch[node - 1];
      for (int g = prev + 1; g <= b0; ++g) g_off[g] = node;
      if (node == N - 1)
        for (int g = b0 + 1; g <= G; ++g) g_off[g] = N;
    }
    lcur[t] = excl;
  }
  __syncthreads();
  for (int p = t; p < cnt; p += 256) {
    unsigned r = edges_tmp[ebase + p];
    int slot = atomicAdd(&lcur[(r >> 16) & 127], 1);
    csr_src[ebase + slot] = (int)(r & 0xffffu);
  }
}

// ---- dense compute ---------------------------------------------------------

// Fused input projection + conv1 GEMM: h = x@W0 + b_in ; hwb = (h@W1)*dis.
__global__ __launch_bounds__(THREADS) void gemm_in_kernel(
    const float* __restrict__ A, const unsigned short* __restrict__ Wt0,
    const float* __restrict__ bias, const unsigned short* __restrict__ Wt1,
    const float* __restrict__ dis, float* __restrict__ hout,
    unsigned short* __restrict__ hwbout, int nrows) {
  __shared__ unsigned short lds[2][32][136];
  int t = threadIdx.x;
  int rbase = blockIdx.x * 32;
  if (rbase >= nrows) return;
#pragma unroll
  for (int i = 0; i < 4; ++i) {
    int fi = i * 256 + t;
    int row = fi >> 5;
    int c4 = fi & 31;
    int gr = rbase + row;
    f32x4 v = (gr < nrows) ? *(const f32x4*)&A[(size_t)gr * 128 + c4 * 4]
                           : (f32x4){0.f, 0.f, 0.f, 0.f};
    ushort4 hh, ll;
    unsigned short h0 = f2bf(v[0]); hh.x = h0; ll.x = f2bf(v[0] - bfval(h0));
    unsigned short h1 = f2bf(v[1]); hh.y = h1; ll.y = f2bf(v[1] - bfval(h1));
    unsigned short h2 = f2bf(v[2]); hh.z = h2; ll.z = f2bf(v[2] - bfval(h2));
    unsigned short h3 = f2bf(v[3]); hh.w = h3; ll.w = f2bf(v[3] - bfval(h3));
    *(ushort4*)&lds[0][row][c4 * 4] = hh;
    *(ushort4*)&lds[1][row][c4 * 4] = ll;
  }
  __syncthreads();
  int wave = t >> 6, lane = t & 63;
  int wr = wave >> 1, cw = wave & 1;
  int lrow = wr * 16 + (lane & 15);
  int hq = lane >> 4;
  int r = rbase + lrow;
  const short8* Wf0 = (const short8*)Wt0;
  const short8* Wf1 = (const short8*)Wt1;

  f32x4 acc[4];
#pragma unroll
  for (int i = 0; i < 4; ++i) acc[i] = (f32x4){0.f, 0.f, 0.f, 0.f};
#pragma unroll
  for (int ks = 0; ks < 4; ++ks) {
    short8 ahi = *(const short8*)&lds[0][lrow][ks * 32 + hq * 8];
    short8 alo = *(const short8*)&lds[1][lrow][ks * 32 + hq * 8];
#pragma unroll
    for (int i = 0; i < 4; ++i) {
      int c16 = cw * 4 + i;
      short8 wh = Wf0[(c16 * 4 + ks) * 64 + lane];
      short8 wl = Wf0[(32 + c16 * 4 + ks) * 64 + lane];
      acc[i] = __builtin_amdgcn_mfma_f32_16x16x32_bf16(wh, ahi, acc[i], 0, 0, 0);
      acc[i] = __builtin_amdgcn_mfma_f32_16x16x32_bf16(wl, ahi, acc[i], 0, 0, 0);
      acc[i] = __builtin_amdgcn_mfma_f32_16x16x32_bf16(wh, alo, acc[i], 0, 0, 0);
    }
  }
  __syncthreads();
#pragma unroll
  for (int i = 0; i < 4; ++i) {
    int fbase = cw * 64 + 16 * i + 4 * hq;
    f32x4 bb = *(const f32x4*)&bias[fbase];
    f32x4 hv;
#pragma unroll
    for (int j = 0; j < 4; ++j) hv[j] = acc[i][j] + bb[j];
    if (r < nrows)
      *(f32x4*)&hout[(size_t)r * 128 + fbase] = hv;
    ushort4 hh, ll;
    unsigned short q0 = f2bf(hv[0]); hh.x = q0; ll.x = f2bf(hv[0] - bfval(q0));
    unsigned short q1 = f2bf(hv[1]); hh.y = q1; ll.y = f2bf(hv[1] - bfval(q1));
    unsigned short q2 = f2bf(hv[2]); hh.z = q2; ll.z = f2bf(hv[2] - bfval(q2));
    unsigned short q3 = f2bf(hv[3]); hh.w = q3; ll.w = f2bf(hv[3] - bfval(q3));
    *(ushort4*)&lds[0][lrow][fbase] = hh;
    *(ushort4*)&lds[1][lrow][fbase] = ll;
  }
  __syncthreads();
#pragma unroll
  for (int i = 0; i < 4; ++i) acc[i] = (f32x4){0.f, 0.f, 0.f, 0.f};
#pragma unroll
  for (int ks = 0; ks < 4; ++ks) {
    short8 ahi = *(const short8*)&lds[0][lrow][ks * 32 + hq * 8];
    short8 alo = *(const short8*)&lds[1][lrow][ks * 32 + hq * 8];
#pragma unroll
    for (int i = 0; i < 4; ++i) {
      int c16 = cw * 4 + i;
      short8 wh = Wf1[(c16 * 4 + ks) * 64 + lane];
      short8 wl = Wf1[(32 + c16 * 4 + ks) * 64 + lane];
      acc[i] = __builtin_amdgcn_mfma_f32_16x16x32_bf16(wh, ahi, acc[i], 0, 0, 0);
      acc[i] = __builtin_amdgcn_mfma_f32_16x16x32_bf16(wl, ahi, acc[i], 0, 0, 0);
      acc[i] = __builtin_amdgcn_mfma_f32_16x16x32_bf16(wh, alo, acc[i], 0, 0, 0);
    }
  }
  if (r >= nrows) return;
  float sc = dis[r];
#pragma unroll
  for (int i = 0; i < 4; ++i) {
    int fbase = cw * 64 + 16 * i + 4 * hq;
    unsigned w0 = ((unsigned)f2bf(acc[i][1] * sc) << 16) |
                  (unsigned)f2bf(acc[i][0] * sc);
    unsigned w1 = ((unsigned)f2bf(acc[i][3] * sc) << 16) |
                  (unsigned)f2bf(acc[i][2] * sc);
    uint2 st; st.x = w0; st.y = w1;
    *(uint2*)&hwbout[(size_t)r * 128 + fbase] = st;
  }
}

// Fused agg + next-layer GEMM. 32 nodes/block (4 waves x 8 nodes).
__global__ __launch_bounds__(THREADS) void agg_gemm_kernel(
    const float* __restrict__ hin, const unsigned short* __restrict__ hwsb,
    const float* __restrict__ bias, const float* __restrict__ dis,
    const int* __restrict__ row_beg, const int* __restrict__ deg,
    const int* __restrict__ csr_src, float* __restrict__ rout,
    const unsigned short* __restrict__ Wt, unsigned short* __restrict__ hwbout,
    int n) {
  __shared__ unsigned short lds[2][32][136];
  int t = threadIdx.x;
  int wave = t >> 6, lane = t & 63;
  int rbase = blockIdx.x * 32;
  int p = lane & 15;
  int qa = (lane >> 4) << 2;
  const char* hwB = (const char*)hwsb;

  for (int i = 0; i < 8; ++i) {
    int lnode = i * 4 + wave;
    int v = rbase + lnode;
    float acc[8];
#pragma unroll
    for (int k = 0; k < 8; ++k) acc[k] = 0.f;
    if (v < n) {
      int b = row_beg[v];
      int pc = (deg[v] + 3) & ~3;
      for (int chunk = 0; chunk < pc; chunk += 64) {
        int m = pc - chunk; if (m > 64) m = 64;
        int idx = csr_src[b + chunk + lane];
        for (int j = 0; j < m; j += 4) {
          int s = __builtin_amdgcn_ds_bpermute((j << 2) + qa, idx);
          uint4 w = *(const uint4*)(hwB + (size_t)s * 256 + p * 16);
          acc[0] += bf_lo(w.x); acc[1] += bf_hi(w.x);
          acc[2] += bf_lo(w.y); acc[3] += bf_hi(w.y);
          acc[4] += bf_lo(w.z); acc[5] += bf_hi(w.z);
          acc[6] += bf_lo(w.w); acc[7] += bf_hi(w.w);
        }
      }
#pragma unroll
      for (int k = 0; k < 8; ++k) {
        acc[k] += __shfl_xor(acc[k], 16, 64);
        acc[k] += __shfl_xor(acc[k], 32, 64);
      }
      if (lane < 16) {
        float dv = dis[v];
        uint4 sw = *(const uint4*)(hwB + (size_t)v * 256 + p * 16);
        float sf[8] = {bf_lo(sw.x), bf_hi(sw.x), bf_lo(sw.y), bf_hi(sw.y),
                       bf_lo(sw.z), bf_hi(sw.z), bf_lo(sw.w), bf_hi(sw.w)};
        f32x4 h0 = *(const f32x4*)&hin[(size_t)v * 128 + p * 8];
        f32x4 h1 = *(const f32x4*)&hin[(size_t)v * 128 + p * 8 + 4];
        f32x4 bb0 = *(const f32x4*)&bias[p * 8];
        f32x4 bb1 = *(const f32x4*)&bias[p * 8 + 4];
        f32x4 o0, o1;
#pragma unroll
        for (int j = 0; j < 4; ++j) {
          o0[j] = fmaxf(h0[j] + dv * (acc[j] + sf[j]) + bb0[j], 0.f);
          o1[j] = fmaxf(h1[j] + dv * (acc[4 + j] + sf[4 + j]) + bb1[j], 0.f);
        }
        *(f32x4*)&rout[(size_t)v * 128 + p * 8] = o0;
        *(f32x4*)&rout[(size_t)v * 128 + p * 8 + 4] = o1;
        ushort4 hh0, ll0, hh1, ll1;
#pragma unroll
        for (int j = 0; j < 4; ++j) {
          unsigned short q0 = f2bf(o0[j]);
          ((unsigned short*)&hh0)[j] = q0;
          ((unsigned short*)&ll0)[j] = f2bf(o0[j] - bfval(q0));
          unsigned short q1 = f2bf(o1[j]);
          ((unsigned short*)&hh1)[j] = q1;
          ((unsigned short*)&ll1)[j] = f2bf(o1[j] - bfval(q1));
        }
        *(ushort4*)&lds[0][lnode][p * 8] = hh0;
        *(ushort4*)&lds[0][lnode][p * 8 + 4] = hh1;
        *(ushort4*)&lds[1][lnode][p * 8] = ll0;
        *(ushort4*)&lds[1][lnode][p * 8 + 4] = ll1;
      }
    } else if (lane < 16) {
      ushort4 z = {0, 0, 0, 0};
      *(ushort4*)&lds[0][lnode][p * 8] = z;
      *(ushort4*)&lds[0][lnode][p * 8 + 4] = z;
      *(ushort4*)&lds[1][lnode][p * 8] = z;
      *(ushort4*)&lds[1][lnode][p * 8 + 4] = z;
    }
  }
  __syncthreads();
  // Phase B: hwb_next = (r @ W) * dis
  int wr = wave >> 1, cw = wave & 1;
  int lrow = wr * 16 + (lane & 15);
  int hq = lane >> 4;
  int r = rbase + lrow;
  const short8* Wf = (const short8*)Wt;
  f32x4 acc[4];
#pragma unroll
  for (int i = 0; i < 4; ++i) acc[i] = (f32x4){0.f, 0.f, 0.f, 0.f};
#pragma unroll
  for (int ks = 0; ks < 4; ++ks) {
    short8 ahi = *(const short8*)&lds[0][lrow][ks * 32 + hq * 8];
    short8 alo = *(const short8*)&lds[1][lrow][ks * 32 + hq * 8];
#pragma unroll
    for (int i = 0; i < 4; ++i) {
      int c16 = cw * 4 + i;
      short8 wh = Wf[(c16 * 4 + ks) * 64 + lane];
      short8 wl = Wf[(32 + c16 * 4 + ks) * 64 + lane];
      acc[i] = __builtin_amdgcn_mfma_f32_16x16x32_bf16(wh, ahi, acc[i], 0, 0, 0);
      acc[i] = __builtin_amdgcn_mfma_f32_16x16x32_bf16(wl, ahi, acc[i], 0, 0, 0);
      acc[i] = __builtin_amdgcn_mfma_f32_16x16x32_bf16(wh, alo, acc[i], 0, 0, 0);
    }
  }
  if (r >= n) return;
  float sc = dis[r];
#pragma unroll
  for (int i = 0; i < 4; ++i) {
    int fbase = cw * 64 + 16 * i + 4 * hq;
    unsigned w0 = ((unsigned)f2bf(acc[i][1] * sc) << 16) |
                  (unsigned)f2bf(acc[i][0] * sc);
    unsigned w1 = ((unsigned)f2bf(acc[i][3] * sc) << 16) |
                  (unsigned)f2bf(acc[i][2] * sc);
    uint2 st; st.x = w0; st.y = w1;
    *(uint2*)&hwbout[(size_t)r * 128 + fbase] = st;
  }
}

// Plain agg for the last conv layer (no following GEMM).
__global__ __launch_bounds__(THREADS) void agg_kernel(
    const float* __restrict__ hin, const unsigned short* __restrict__ hwsb,
    const float* __restrict__ bias, const float* __restrict__ dis,
    const int* __restrict__ row_beg, const int* __restrict__ deg,
    const int* __restrict__ csr_src, float* __restrict__ out, int n) {
  int v = (blockIdx.x * THREADS + threadIdx.x) >> 6;
  int lane = threadIdx.x & 63;
  if (v >= n) return;
  int p = lane & 15;
  int qa = (lane >> 4) << 2;
  const char* hwB = (const char*)hwsb;
  float acc[8];
#pragma unroll
  for (int i = 0; i < 8; ++i) acc[i] = 0.f;
  int b = row_beg[v];
  int pc = (deg[v] + 3) & ~3;
  for (int chunk = 0; chunk < pc; chunk += 64) {
    int m = pc - chunk; if (m > 64) m = 64;
    int idx = csr_src[b + chunk + lane];
    for (int j = 0; j < m; j += 4) {
      int s = __builtin_amdgcn_ds_bpermute((j << 2) + qa, idx);
      uint4 w = *(const uint4*)(hwB + (size_t)s * 256 + p * 16);
      acc[0] += bf_lo(w.x); acc[1] += bf_hi(w.x);
      acc[2] += bf_lo(w.y); acc[3] += bf_hi(w.y);
      acc[4] += bf_lo(w.z); acc[5] += bf_hi(w.z);
      acc[6] += bf_lo(w.w); acc[7] += bf_hi(w.w);
    }
  }
#pragma unroll
  for (int i = 0; i < 8; ++i) {
    acc[i] += __shfl_xor(acc[i], 16, 64);
    acc[i] += __shfl_xor(acc[i], 32, 64);
  }
  if (lane < 16) {
    float dv = dis[v];
    uint4 sw = *(const uint4*)(hwB + (size_t)v * 256 + p * 16);
    float sf[8] = {bf_lo(sw.x), bf_hi(sw.x), bf_lo(sw.y), bf_hi(sw.y),
                   bf_lo(sw.z), bf_hi(sw.z), bf_lo(sw.w), bf_hi(sw.w)};
    f32x4 h0 = *(const f32x4*)&hin[(size_t)v * 128 + p * 8];
    f32x4 h1 = *(const f32x4*)&hin[(size_t)v * 128 + p * 8 + 4];
    f32x4 bb0 = *(const f32x4*)&bias[p * 8];
    f32x4 bb1 = *(const f32x4*)&bias[p * 8 + 4];
    f32x4 o0, o1;
#pragma unroll
    for (int j = 0; j < 4; ++j) {
      o0[j] = fmaxf(h0[j] + dv * (acc[j] + sf[j]) + bb0[j], 0.f);
      o1[j] = fmaxf(h1[j] + dv * (acc[4 + j] + sf[4 + j]) + bb1[j], 0.f);
    }
    *(f32x4*)&out[(size_t)v * 128 + p * 8] = o0;
    *(f32x4*)&out[(size_t)v * 128 + p * 8 + 4] = o1;
  }
}

// Fused pool + head: 16 node sub-streams x 32 float4 feature lanes.
__global__ __launch_bounds__(512) void pool_head_kernel(
    const float* __restrict__ r1, const float* __restrict__ r2,
    const float* __restrict__ r3, const int* __restrict__ g_off,
    const float* __restrict__ Wp1, const float* __restrict__ bp1,
    const float* __restrict__ Wp2, const float* __restrict__ bp2,
    float* __restrict__ out) {
  __shared__ float red[16][384];
  __shared__ float ps[384];
  __shared__ float t1[128];
  __shared__ float wsum[2];
  int g = blockIdx.x, t = threadIdx.x;
  int sub = t >> 5;
  int c4 = t & 31;
  int beg = g_off[g], end = g_off[g + 1];
  f32x4 s1 = {0.f, 0.f, 0.f, 0.f}, s2 = s1, s3 = s1;
  for (int i = beg + sub; i < end; i += 16) {
    size_t o = (size_t)i * 128 + c4 * 4;
    f32x4 a = *(const f32x4*)&r1[o];
    f32x4 b = *(const f32x4*)&r2[o];
    f32x4 c = *(const f32x4*)&r3[o];
#pragma unroll
    for (int j = 0; j < 4; ++j) { s1[j] += a[j]; s2[j] += b[j]; s3[j] += c[j]; }
  }
#pragma unroll
  for (int j = 0; j < 4; ++j) {
    red[sub][c4 * 4 + j] = s1[j];
    red[sub][128 + c4 * 4 + j] = s2[j];
    red[sub][256 + c4 * 4 + j] = s3[j];
  }
  __syncthreads();
  if (t < 384) {
    float inv = 1.0f / fmaxf((float)(end - beg), 1.0f);
    float s = 0.f;
#pragma unroll
    for (int k = 0; k < 16; ++k) s += red[k][t];
    ps[t] = s * inv;
  }
  __syncthreads();
  if (t < 128) {
    float acc = bp1[t];
    for (int k = 0; k < 384; ++k) acc += ps[k] * Wp1[k * 128 + t];
    t1[t] = fmaxf(acc, 0.f);
  }
  __syncthreads();
  if (t < 128) {
    float acc2 = bp2[t];
    for (int k = 0; k < 128; ++k) acc2 += t1[k] * Wp2[k * 128 + t];
    float ss = acc2 * acc2;
    for (int off = 32; off > 0; off >>= 1) ss += __shfl_down(ss, off, 64);
    if ((t & 63) == 0) wsum[t >> 6] = ss;
    __syncthreads();
    float nrm = sqrtf(wsum[0] + wsum[1]);
    out[g * 128 + t] = acc2 / fmaxf(nrm, 1e-12f);
  }
}

static inline size_t align256(size_t x) { return (x + 255) & ~(size_t)255; }

extern "C" void kernel_launch(void* const* d_in, const int* in_sizes, int n_in,
                              void* d_out, int out_size, void* d_ws, size_t ws_size,
                              hipStream_t stream) {
  const float* x     = (const float*)d_in[0];
  const int*   ei    = (const int*)d_in[1];
  const int*   batch = (const int*)d_in[2];
  const float* W_in  = (const float*)d_in[3];
  const float* b_in  = (const float*)d_in[4];
  const float* W1    = (const float*)d_in[5];
  const float* b1    = (const float*)d_in[6];
  const float* W2    = (const float*)d_in[7];
  const float* b2    = (const float*)d_in[8];
  const float* W3    = (const float*)d_in[9];
  const float* b3    = (const float*)d_in[10];
  const float* Wp1   = (const float*)d_in[11];
  const float* bp1   = (const float*)d_in[12];
  const float* Wp2   = (const float*)d_in[13];
  const float* bp2   = (const float*)d_in[14];
  float* out = (float*)d_out;

  const int N = in_sizes[0] / 128;
  const int E = in_sizes[1] / 2;
  const int G = out_size / 128;
  const int* src = ei;
  const int* dst = ei + E;
  const int NB = (N + 127) / 128;
  const int CBLKS = (E + 2047) / 2048;

  char* p = (char*)d_ws;
  auto carve = [&](size_t bytes) { char* r = p; p += align256(bytes); return (void*)r; };
  int*   bkt_cursor = (int*)carve((size_t)NB * 4);
  int*   g_off      = (int*)carve((size_t)(G + 1) * 4);
  int*   row_beg    = (int*)carve((size_t)N * 4);
  int*   deg        = (int*)carve((size_t)N * 4);
  unsigned* edges_tmp = (unsigned*)carve((size_t)NB * BCAP * 4);
  int*   csr_src    = (int*)carve((size_t)NB * BCAP * 4);
  float* dis        = (float*)carve((size_t)N * 4);
  unsigned short* Wtb = (unsigned short*)carve((size_t)4 * 2 * 128 * 128 * 2);
  float* h   = (float*)carve((size_t)N * 128 * 4);
  float* r1  = (float*)carve((size_t)N * 128 * 4);
  float* r2  = (float*)carve((size_t)N * 128 * 4);
  float* r3  = (float*)carve((size_t)N * 128 * 4);
  unsigned short* hwbA = (unsigned short*)carve((size_t)(N + 1) * 128 * 2);
  unsigned short* hwbB = (unsigned short*)carve((size_t)(N + 1) * 128 * 2);
  (void)ws_size; (void)n_in;

  hipMemsetAsync(bkt_cursor, 0, (size_t)NB * 4, stream);

  bucket_fill_kernel<<<CBLKS + 256, THREADS, 0, stream>>>(
      src, dst, bkt_cursor, edges_tmp, E, W_in, W1, W2, W3, Wtb);
  node_sort_kernel<<<NB, THREADS, 0, stream>>>(
      edges_tmp, bkt_cursor, batch, row_beg, deg, dis, csr_src, g_off,
      (unsigned*)hwbA, (unsigned*)hwbB, N, G);

  int tileBlocks = (N + 31) / 32;
  int aggBlocks = (N + 3) / 4;

  const unsigned short* Wt0 = Wtb;
  const unsigned short* Wt1 = Wtb + 32768;
  const unsigned short* Wt2 = Wtb + 2 * 32768;
  const unsigned short* Wt3 = Wtb + 3 * 32768;

  // h = x@W_in + b_in ; hwbA = (h@W1)*dis
  gemm_in_kernel<<<tileBlocks, THREADS, 0, stream>>>(
      x, Wt0, b_in, Wt1, dis, h, hwbA, N);
  // r1 = relu(h + dis*(gatherA+selfA) + b1) ; hwbB = (r1@W2)*dis
  agg_gemm_kernel<<<tileBlocks, THREADS, 0, stream>>>(
      h, hwbA, b1, dis, row_beg, deg, csr_src, r1, Wt2, hwbB, N);
  // r2 = relu(r1 + dis*(gatherB+selfB) + b2) ; hwbA = (r2@W3)*dis
  agg_gemm_kernel<<<tileBlocks, THREADS, 0, stream>>>(
      r1, hwbB, b2, dis, row_beg, deg, csr_src, r2, Wt3, hwbA, N);
  // r3 = relu(r2 + dis*(gatherA+selfA) + b3)
  agg_kernel<<<aggBlocks, THREADS, 0, stream>>>(
      r2, hwbA, b3, dis, row_beg, deg, csr_src, r3, N);

  pool_head_kernel<<<G, 512, 0, stream>>>(
      r1, r2, r3, g_off, Wp1, bp1, Wp2, bp2, out);
}

// Round 13
// 232.590 us; speedup vs baseline: 1.1095x; 1.1095x over previous
//
#include <hip/hip_runtime.h>
#include <hip/hip_bf16.h>

// ---------------------------------------------------------------------------
// Encoder3: 3-layer GCN + JK-cat + mean-pool + projection head + L2 normalize
//   - CSR build: direct bucketed fill (+fused wconv tail) + per-bucket sort.
//   - Residual stream fp32; gathered message buffer (hws) bf16 + zero row N.
//   - gemm_in: x->h->hwb fused (LDS round-trip).
//   - conv GEMMs: split-precision MFMA (hi/lo bf16, 3 MFMAs), fragment-major
//     W, 32-row LDS-staged A tile.
//   - Aggregation: one wave per node, 4 edges per dwordx4 gather (bpermute
//     index spread) — measured structural floor of the random-gather path.
//   - Pool + head fused.
// Requires N < 65536 (16-bit packing) and NB <= 512.
// R12 lesson: do NOT fuse agg->gemm (8x serial gather per wave + occupancy
// drop 63->34% regressed 233->258). Keep latency-bound gather maximally
// wave-parallel.
// ---------------------------------------------------------------------------

#define THREADS 256
#define BCAP 4096

typedef __attribute__((ext_vector_type(8))) short short8;   // 8 bf16
typedef __attribute__((ext_vector_type(4))) float f32x4;

static __device__ __forceinline__ unsigned short f2bf(float f) {
  unsigned u = __float_as_uint(f);
  u += 0x7fffu + ((u >> 16) & 1u);   // RNE
  return (unsigned short)(u >> 16);
}
static __device__ __forceinline__ float bfval(unsigned short h) {
  return __uint_as_float((unsigned)h << 16);
}
static __device__ __forceinline__ float bf_lo(unsigned w) {
  return __uint_as_float(w << 16);
}
static __device__ __forceinline__ float bf_hi(unsigned w) {
  return __uint_as_float(w & 0xffff0000u);
}

// ---- CSR build (+fused wconv) ----------------------------------------------

__global__ __launch_bounds__(THREADS) void bucket_fill_kernel(
    const int* __restrict__ src, const int* __restrict__ dst,
    int* __restrict__ bkt_cursor, unsigned* __restrict__ edges_tmp, int E,
    const float* __restrict__ W0, const float* __restrict__ W1,
    const float* __restrict__ W2, const float* __restrict__ W3,
    unsigned short* __restrict__ Wtb) {
  __shared__ int hist[512];
  __shared__ int excl[512];
  __shared__ int gbase[512];
  __shared__ unsigned staging[2048];
  int t = threadIdx.x;
  int base = blockIdx.x * 2048;
  if (base >= E) {
    int cb = (E + 2047) >> 11;
    int tid = (blockIdx.x - cb) * THREADS + t;
    if (tid < 4 * 128 * 128) {
      int w = tid >> 14, c = (tid >> 7) & 127, k = tid & 127;
      const float* W = (w == 0) ? W0 : (w == 1) ? W1 : (w == 2) ? W2 : W3;
      float f = W[k * 128 + c];
      unsigned short hi = f2bf(f);
      unsigned short lo = f2bf(f - bfval(hi));
      int c16 = c >> 4, lc = c & 15;
      int ks = k >> 5, hq = (k >> 3) & 3, j = k & 7;
      int lane = hq * 16 + lc;
      size_t wb = (size_t)w * 32768;
      size_t fidx = (size_t)((c16 * 4 + ks) * 64 + lane) * 8 + j;
      Wtb[wb + fidx] = hi;
      Wtb[wb + 16384 + fidx] = lo;
    }
    return;
  }
  hist[t] = 0; hist[t + 256] = 0;
  __syncthreads();
  int e0 = base + t * 8;
  int ds[8], ss[8];
  if (e0 + 7 < E) {
    *(int4*)&ds[0] = *(const int4*)&dst[e0];
    *(int4*)&ds[4] = *(const int4*)&dst[e0 + 4];
    *(int4*)&ss[0] = *(const int4*)&src[e0];
    *(int4*)&ss[4] = *(const int4*)&src[e0 + 4];
  } else {
#pragma unroll
    for (int k = 0; k < 8; ++k) {
      ds[k] = (e0 + k < E) ? dst[e0 + k] : -1;
      ss[k] = (e0 + k < E) ? src[e0 + k] : 0;
    }
  }
  unsigned rec[8]; int bk[8]; int slot[8];
#pragma unroll
  for (int k = 0; k < 8; ++k) {
    bk[k] = -1;
    if (ds[k] >= 0) {
      rec[k] = ((unsigned)ds[k] << 16) | (unsigned)ss[k];
      bk[k] = ds[k] >> 7;
      slot[k] = atomicAdd(&hist[bk[k]], 1);
    }
  }
  __syncthreads();
  int v0 = hist[t], v1 = hist[t + 256];
  excl[t] = v0; excl[t + 256] = v1;
  __syncthreads();
  for (int off = 1; off < 512; off <<= 1) {
    int a = (t >= off) ? excl[t - off] : 0;
    int b = excl[t + 256 - off];
    __syncthreads();
    excl[t] += a; excl[t + 256] += b;
    __syncthreads();
  }
  int e0x = excl[t] - v0, e1x = excl[t + 256] - v1;
  __syncthreads();
  excl[t] = e0x; excl[t + 256] = e1x;
  __syncthreads();
#pragma unroll
  for (int k = 0; k < 8; ++k)
    if (bk[k] >= 0) staging[excl[bk[k]] + slot[k]] = rec[k];
  if (v0) gbase[t] = atomicAdd(&bkt_cursor[t], v0);
  if (v1) gbase[t + 256] = atomicAdd(&bkt_cursor[t + 256], v1);
  __syncthreads();
  int total = (base + 2048 <= E) ? 2048 : (E - base);
  for (int p = t; p < total; p += 256) {
    unsigned r = staging[p];
    int b = (int)(r >> 23);
    int pos = gbase[b] + (p - excl[b]);
    if (pos < BCAP)
      edges_tmp[(size_t)b * BCAP + pos] = r;
  }
}

__global__ __launch_bounds__(THREADS) void node_sort_kernel(
    const unsigned* __restrict__ edges_tmp, const int* __restrict__ bkt_cursor,
    const int* __restrict__ batch, int* __restrict__ row_beg,
    int* __restrict__ deg, float* __restrict__ dis,
    int* __restrict__ csr_src, int* __restrict__ g_off,
    unsigned* __restrict__ hwb_w, int N, int G) {
  __shared__ int lhist[128];
  __shared__ int lbase[128];
  __shared__ int lcur[128];
  int b = blockIdx.x, t = threadIdx.x;
  if (b == 0 && t >= 128 && t < 192)
    hwb_w[(size_t)N * 64 + (t - 128)] = 0;   // sentinel zero row (256 B)
  int cnt = bkt_cursor[b];
  if (cnt > BCAP) cnt = BCAP;
  size_t ebase = (size_t)b * BCAP;
  if (t < 128) lhist[t] = 0;
  __syncthreads();
  for (int p = t; p < cnt; p += 256)
    atomicAdd(&lhist[(edges_tmp[ebase + p] >> 16) & 127], 1);
  __syncthreads();
  int pad = 0;
  if (t < 128) {
    pad = (lhist[t] + 3) & ~3;
    lbase[t] = pad;
  }
  __syncthreads();
  for (int off = 1; off < 128; off <<= 1) {
    int a = (t >= off && t < 128) ? lbase[t - off] : 0;
    __syncthreads();
    if (t < 128) lbase[t] += a;
    __syncthreads();
  }
  if (t < 128) {
    int excl = lbase[t] - pad;
    int node = b * 128 + t;
    if (node < N) {
      row_beg[node] = (int)ebase + excl;
      deg[node] = lhist[t];
      dis[node] = rsqrtf((float)lhist[t] + 1.0f);
      for (int q = lhist[t]; q < pad; ++q)
        csr_src[ebase + excl + q] = N;
      int b0 = batch[node];
      int prev = (node == 0) ? -1 : batch[node - 1];
      for (int g = prev + 1; g <= b0; ++g) g_off[g] = node;
      if (node == N - 1)
        for (int g = b0 + 1; g <= G; ++g) g_off[g] = N;
    }
    lcur[t] = excl;
  }
  __syncthreads();
  for (int p = t; p < cnt; p += 256) {
    unsigned r = edges_tmp[ebase + p];
    int slot = atomicAdd(&lcur[(r >> 16) & 127], 1);
    csr_src[ebase + slot] = (int)(r & 0xffffu);
  }
}

// ---- dense compute ---------------------------------------------------------

// Fused input projection + conv1 GEMM: h = x@W0 + b_in ; hwb = (h@W1)*dis.
__global__ __launch_bounds__(THREADS) void gemm_in_kernel(
    const float* __restrict__ A, const unsigned short* __restrict__ Wt0,
    const float* __restrict__ bias, const unsigned short* __restrict__ Wt1,
    const float* __restrict__ dis, float* __restrict__ hout,
    unsigned short* __restrict__ hwbout, int nrows) {
  __shared__ unsigned short lds[2][32][136];
  int t = threadIdx.x;
  int rbase = blockIdx.x * 32;
  if (rbase >= nrows) return;
#pragma unroll
  for (int i = 0; i < 4; ++i) {
    int fi = i * 256 + t;
    int row = fi >> 5;
    int c4 = fi & 31;
    int gr = rbase + row;
    f32x4 v = (gr < nrows) ? *(const f32x4*)&A[(size_t)gr * 128 + c4 * 4]
                           : (f32x4){0.f, 0.f, 0.f, 0.f};
    ushort4 hh, ll;
    unsigned short h0 = f2bf(v[0]); hh.x = h0; ll.x = f2bf(v[0] - bfval(h0));
    unsigned short h1 = f2bf(v[1]); hh.y = h1; ll.y = f2bf(v[1] - bfval(h1));
    unsigned short h2 = f2bf(v[2]); hh.z = h2; ll.z = f2bf(v[2] - bfval(h2));
    unsigned short h3 = f2bf(v[3]); hh.w = h3; ll.w = f2bf(v[3] - bfval(h3));
    *(ushort4*)&lds[0][row][c4 * 4] = hh;
    *(ushort4*)&lds[1][row][c4 * 4] = ll;
  }
  __syncthreads();
  int wave = t >> 6, lane = t & 63;
  int wr = wave >> 1, cw = wave & 1;
  int lrow = wr * 16 + (lane & 15);
  int hq = lane >> 4;
  int r = rbase + lrow;
  const short8* Wf0 = (const short8*)Wt0;
  const short8* Wf1 = (const short8*)Wt1;

  f32x4 acc[4];
#pragma unroll
  for (int i = 0; i < 4; ++i) acc[i] = (f32x4){0.f, 0.f, 0.f, 0.f};
#pragma unroll
  for (int ks = 0; ks < 4; ++ks) {
    short8 ahi = *(const short8*)&lds[0][lrow][ks * 32 + hq * 8];
    short8 alo = *(const short8*)&lds[1][lrow][ks * 32 + hq * 8];
#pragma unroll
    for (int i = 0; i < 4; ++i) {
      int c16 = cw * 4 + i;
      short8 wh = Wf0[(c16 * 4 + ks) * 64 + lane];
      short8 wl = Wf0[(32 + c16 * 4 + ks) * 64 + lane];
      acc[i] = __builtin_amdgcn_mfma_f32_16x16x32_bf16(wh, ahi, acc[i], 0, 0, 0);
      acc[i] = __builtin_amdgcn_mfma_f32_16x16x32_bf16(wl, ahi, acc[i], 0, 0, 0);
      acc[i] = __builtin_amdgcn_mfma_f32_16x16x32_bf16(wh, alo, acc[i], 0, 0, 0);
    }
  }
  __syncthreads();
#pragma unroll
  for (int i = 0; i < 4; ++i) {
    int fbase = cw * 64 + 16 * i + 4 * hq;
    f32x4 bb = *(const f32x4*)&bias[fbase];
    f32x4 hv;
#pragma unroll
    for (int j = 0; j < 4; ++j) hv[j] = acc[i][j] + bb[j];
    if (r < nrows)
      *(f32x4*)&hout[(size_t)r * 128 + fbase] = hv;
    ushort4 hh, ll;
    unsigned short q0 = f2bf(hv[0]); hh.x = q0; ll.x = f2bf(hv[0] - bfval(q0));
    unsigned short q1 = f2bf(hv[1]); hh.y = q1; ll.y = f2bf(hv[1] - bfval(q1));
    unsigned short q2 = f2bf(hv[2]); hh.z = q2; ll.z = f2bf(hv[2] - bfval(q2));
    unsigned short q3 = f2bf(hv[3]); hh.w = q3; ll.w = f2bf(hv[3] - bfval(q3));
    *(ushort4*)&lds[0][lrow][fbase] = hh;
    *(ushort4*)&lds[1][lrow][fbase] = ll;
  }
  __syncthreads();
#pragma unroll
  for (int i = 0; i < 4; ++i) acc[i] = (f32x4){0.f, 0.f, 0.f, 0.f};
#pragma unroll
  for (int ks = 0; ks < 4; ++ks) {
    short8 ahi = *(const short8*)&lds[0][lrow][ks * 32 + hq * 8];
    short8 alo = *(const short8*)&lds[1][lrow][ks * 32 + hq * 8];
#pragma unroll
    for (int i = 0; i < 4; ++i) {
      int c16 = cw * 4 + i;
      short8 wh = Wf1[(c16 * 4 + ks) * 64 + lane];
      short8 wl = Wf1[(32 + c16 * 4 + ks) * 64 + lane];
      acc[i] = __builtin_amdgcn_mfma_f32_16x16x32_bf16(wh, ahi, acc[i], 0, 0, 0);
      acc[i] = __builtin_amdgcn_mfma_f32_16x16x32_bf16(wl, ahi, acc[i], 0, 0, 0);
      acc[i] = __builtin_amdgcn_mfma_f32_16x16x32_bf16(wh, alo, acc[i], 0, 0, 0);
    }
  }
  if (r >= nrows) return;
  float sc = dis[r];
#pragma unroll
  for (int i = 0; i < 4; ++i) {
    int fbase = cw * 64 + 16 * i + 4 * hq;
    unsigned w0 = ((unsigned)f2bf(acc[i][1] * sc) << 16) |
                  (unsigned)f2bf(acc[i][0] * sc);
    unsigned w1 = ((unsigned)f2bf(acc[i][3] * sc) << 16) |
                  (unsigned)f2bf(acc[i][2] * sc);
    uint2 st; st.x = w0; st.y = w1;
    *(uint2*)&hwbout[(size_t)r * 128 + fbase] = st;
  }
}

// out[r][c] = ((A[r] @ W)[c] + bias[c]?) * scale[r]?
template <int OUT_FP32>
__global__ __launch_bounds__(THREADS) void gemm_mfma(
    const float* __restrict__ A, const unsigned short* __restrict__ Wt,
    const float* __restrict__ bias, const float* __restrict__ scale,
    void* __restrict__ outv, int nrows) {
  __shared__ unsigned short lds[2][32][136];
  int t = threadIdx.x;
  int rbase = blockIdx.x * 32;
  if (rbase >= nrows) return;
#pragma unroll
  for (int i = 0; i < 4; ++i) {
    int fi = i * 256 + t;
    int row = fi >> 5;
    int c4 = fi & 31;
    int gr = rbase + row;
    f32x4 v = (gr < nrows) ? *(const f32x4*)&A[(size_t)gr * 128 + c4 * 4]
                           : (f32x4){0.f, 0.f, 0.f, 0.f};
    ushort4 hh, ll;
    unsigned short h0 = f2bf(v[0]); hh.x = h0; ll.x = f2bf(v[0] - bfval(h0));
    unsigned short h1 = f2bf(v[1]); hh.y = h1; ll.y = f2bf(v[1] - bfval(h1));
    unsigned short h2 = f2bf(v[2]); hh.z = h2; ll.z = f2bf(v[2] - bfval(h2));
    unsigned short h3 = f2bf(v[3]); hh.w = h3; ll.w = f2bf(v[3] - bfval(h3));
    *(ushort4*)&lds[0][row][c4 * 4] = hh;
    *(ushort4*)&lds[1][row][c4 * 4] = ll;
  }
  __syncthreads();
  int wave = t >> 6, lane = t & 63;
  int wr = wave >> 1, cw = wave & 1;
  int lrow = wr * 16 + (lane & 15);
  int hq = lane >> 4;
  int r = rbase + lrow;
  const short8* Wf = (const short8*)Wt;

  f32x4 acc[4];
#pragma unroll
  for (int i = 0; i < 4; ++i) acc[i] = (f32x4){0.f, 0.f, 0.f, 0.f};
#pragma unroll
  for (int ks = 0; ks < 4; ++ks) {
    short8 ahi = *(const short8*)&lds[0][lrow][ks * 32 + hq * 8];
    short8 alo = *(const short8*)&lds[1][lrow][ks * 32 + hq * 8];
#pragma unroll
    for (int i = 0; i < 4; ++i) {
      int c16 = cw * 4 + i;
      short8 wh = Wf[(c16 * 4 + ks) * 64 + lane];
      short8 wl = Wf[(32 + c16 * 4 + ks) * 64 + lane];
      acc[i] = __builtin_amdgcn_mfma_f32_16x16x32_bf16(wh, ahi, acc[i], 0, 0, 0);
      acc[i] = __builtin_amdgcn_mfma_f32_16x16x32_bf16(wl, ahi, acc[i], 0, 0, 0);
      acc[i] = __builtin_amdgcn_mfma_f32_16x16x32_bf16(wh, alo, acc[i], 0, 0, 0);
    }
  }
  if (r >= nrows) return;
  float sc = scale ? scale[r] : 1.0f;
#pragma unroll
  for (int i = 0; i < 4; ++i) {
    int fbase = cw * 64 + 16 * i + 4 * hq;
    float b4[4] = {0.f, 0.f, 0.f, 0.f};
    if (bias) {
      f32x4 bb = *(const f32x4*)&bias[fbase];
      b4[0] = bb[0]; b4[1] = bb[1]; b4[2] = bb[2]; b4[3] = bb[3];
    }
    if (OUT_FP32) {
      f32x4 o;
#pragma unroll
      for (int j = 0; j < 4; ++j) o[j] = (acc[i][j] + b4[j]) * sc;
      *(f32x4*)&((float*)outv)[(size_t)r * 128 + fbase] = o;
    } else {
      unsigned w0 = ((unsigned)f2bf((acc[i][1] + b4[1]) * sc) << 16) |
                    (unsigned)f2bf((acc[i][0] + b4[0]) * sc);
      unsigned w1 = ((unsigned)f2bf((acc[i][3] + b4[3]) * sc) << 16) |
                    (unsigned)f2bf((acc[i][2] + b4[2]) * sc);
      uint2 st; st.x = w0; st.y = w1;
      *(uint2*)&((unsigned short*)outv)[(size_t)r * 128 + fbase] = st;
    }
  }
}

// out = relu(hin + dis[v]*(sum_{src} hws[src] + hws[v]) + bias)
// One wave per node; 4 edges per dwordx4 gather (bpermute index spread);
// padded edge lists (x4, sentinel row N); shfl_xor fold.
__global__ __launch_bounds__(THREADS) void agg_kernel(
    const float* __restrict__ hin, const unsigned short* __restrict__ hwsb,
    const float* __restrict__ bias, const float* __restrict__ dis,
    const int* __restrict__ row_beg, const int* __restrict__ deg,
    const int* __restrict__ csr_src, float* __restrict__ out, int n) {
  int v = (blockIdx.x * THREADS + threadIdx.x) >> 6;
  int lane = threadIdx.x & 63;
  if (v >= n) return;
  int p = lane & 15;
  int qa = (lane >> 4) << 2;
  const char* hwB = (const char*)hwsb;
  float acc[8];
#pragma unroll
  for (int i = 0; i < 8; ++i) acc[i] = 0.f;
  int b = row_beg[v];
  int pc = (deg[v] + 3) & ~3;
  for (int chunk = 0; chunk < pc; chunk += 64) {
    int m = pc - chunk; if (m > 64) m = 64;
    int idx = csr_src[b + chunk + lane];
    for (int j = 0; j < m; j += 4) {
      int s = __builtin_amdgcn_ds_bpermute((j << 2) + qa, idx);
      uint4 w = *(const uint4*)(hwB + (size_t)s * 256 + p * 16);
      acc[0] += bf_lo(w.x); acc[1] += bf_hi(w.x);
      acc[2] += bf_lo(w.y); acc[3] += bf_hi(w.y);
      acc[4] += bf_lo(w.z); acc[5] += bf_hi(w.z);
      acc[6] += bf_lo(w.w); acc[7] += bf_hi(w.w);
    }
  }
#pragma unroll
  for (int i = 0; i < 8; ++i) {
    acc[i] += __shfl_xor(acc[i], 16, 64);
    acc[i] += __shfl_xor(acc[i], 32, 64);
  }
  if (lane < 16) {
    float dv = dis[v];
    uint4 sw = *(const uint4*)(hwB + (size_t)v * 256 + p * 16);
    float sf[8] = {bf_lo(sw.x), bf_hi(sw.x), bf_lo(sw.y), bf_hi(sw.y),
                   bf_lo(sw.z), bf_hi(sw.z), bf_lo(sw.w), bf_hi(sw.w)};
    f32x4 h0 = *(const f32x4*)&hin[(size_t)v * 128 + p * 8];
    f32x4 h1 = *(const f32x4*)&hin[(size_t)v * 128 + p * 8 + 4];
    f32x4 bb0 = *(const f32x4*)&bias[p * 8];
    f32x4 bb1 = *(const f32x4*)&bias[p * 8 + 4];
    f32x4 o0, o1;
#pragma unroll
    for (int j = 0; j < 4; ++j) {
      o0[j] = fmaxf(h0[j] + dv * (acc[j] + sf[j]) + bb0[j], 0.f);
      o1[j] = fmaxf(h1[j] + dv * (acc[4 + j] + sf[4 + j]) + bb1[j], 0.f);
    }
    *(f32x4*)&out[(size_t)v * 128 + p * 8] = o0;
    *(f32x4*)&out[(size_t)v * 128 + p * 8 + 4] = o1;
  }
}

// Fused pool + head: 16 node sub-streams x 32 float4 feature lanes.
__global__ __launch_bounds__(512) void pool_head_kernel(
    const float* __restrict__ r1, const float* __restrict__ r2,
    const float* __restrict__ r3, const int* __restrict__ g_off,
    const float* __restrict__ Wp1, const float* __restrict__ bp1,
    const float* __restrict__ Wp2, const float* __restrict__ bp2,
    float* __restrict__ out) {
  __shared__ float red[16][384];
  __shared__ float ps[384];
  __shared__ float t1[128];
  __shared__ float wsum[2];
  int g = blockIdx.x, t = threadIdx.x;
  int sub = t >> 5;
  int c4 = t & 31;
  int beg = g_off[g], end = g_off[g + 1];
  f32x4 s1 = {0.f, 0.f, 0.f, 0.f}, s2 = s1, s3 = s1;
  for (int i = beg + sub; i < end; i += 16) {
    size_t o = (size_t)i * 128 + c4 * 4;
    f32x4 a = *(const f32x4*)&r1[o];
    f32x4 b = *(const f32x4*)&r2[o];
    f32x4 c = *(const f32x4*)&r3[o];
#pragma unroll
    for (int j = 0; j < 4; ++j) { s1[j] += a[j]; s2[j] += b[j]; s3[j] += c[j]; }
  }
#pragma unroll
  for (int j = 0; j < 4; ++j) {
    red[sub][c4 * 4 + j] = s1[j];
    red[sub][128 + c4 * 4 + j] = s2[j];
    red[sub][256 + c4 * 4 + j] = s3[j];
  }
  __syncthreads();
  if (t < 384) {
    float inv = 1.0f / fmaxf((float)(end - beg), 1.0f);
    float s = 0.f;
#pragma unroll
    for (int k = 0; k < 16; ++k) s += red[k][t];
    ps[t] = s * inv;
  }
  __syncthreads();
  if (t < 128) {
    float acc = bp1[t];
    for (int k = 0; k < 384; ++k) acc += ps[k] * Wp1[k * 128 + t];
    t1[t] = fmaxf(acc, 0.f);
  }
  __syncthreads();
  if (t < 128) {
    float acc2 = bp2[t];
    for (int k = 0; k < 128; ++k) acc2 += t1[k] * Wp2[k * 128 + t];
    float ss = acc2 * acc2;
    for (int off = 32; off > 0; off >>= 1) ss += __shfl_down(ss, off, 64);
    if ((t & 63) == 0) wsum[t >> 6] = ss;
    __syncthreads();
    float nrm = sqrtf(wsum[0] + wsum[1]);
    out[g * 128 + t] = acc2 / fmaxf(nrm, 1e-12f);
  }
}

static inline size_t align256(size_t x) { return (x + 255) & ~(size_t)255; }

extern "C" void kernel_launch(void* const* d_in, const int* in_sizes, int n_in,
                              void* d_out, int out_size, void* d_ws, size_t ws_size,
                              hipStream_t stream) {
  const float* x     = (const float*)d_in[0];
  const int*   ei    = (const int*)d_in[1];
  const int*   batch = (const int*)d_in[2];
  const float* W_in  = (const float*)d_in[3];
  const float* b_in  = (const float*)d_in[4];
  const float* W1    = (const float*)d_in[5];
  const float* b1    = (const float*)d_in[6];
  const float* W2    = (const float*)d_in[7];
  const float* b2    = (const float*)d_in[8];
  const float* W3    = (const float*)d_in[9];
  const float* b3    = (const float*)d_in[10];
  const float* Wp1   = (const float*)d_in[11];
  const float* bp1   = (const float*)d_in[12];
  const float* Wp2   = (const float*)d_in[13];
  const float* bp2   = (const float*)d_in[14];
  float* out = (float*)d_out;

  const int N = in_sizes[0] / 128;
  const int E = in_sizes[1] / 2;
  const int G = out_size / 128;
  const int* src = ei;
  const int* dst = ei + E;
  const int NB = (N + 127) / 128;
  const int CBLKS = (E + 2047) / 2048;

  char* p = (char*)d_ws;
  auto carve = [&](size_t bytes) { char* r = p; p += align256(bytes); return (void*)r; };
  int*   bkt_cursor = (int*)carve((size_t)NB * 4);
  int*   g_off      = (int*)carve((size_t)(G + 1) * 4);
  int*   row_beg    = (int*)carve((size_t)N * 4);
  int*   deg        = (int*)carve((size_t)N * 4);
  unsigned* edges_tmp = (unsigned*)carve((size_t)NB * BCAP * 4);
  int*   csr_src    = (int*)carve((size_t)NB * BCAP * 4);
  float* dis        = (float*)carve((size_t)N * 4);
  unsigned short* Wtb = (unsigned short*)carve((size_t)4 * 2 * 128 * 128 * 2);
  float* h   = (float*)carve((size_t)N * 128 * 4);
  float* r1  = (float*)carve((size_t)N * 128 * 4);
  float* r2  = (float*)carve((size_t)N * 128 * 4);
  float* r3  = (float*)carve((size_t)N * 128 * 4);
  unsigned short* hwb = (unsigned short*)carve((size_t)(N + 1) * 128 * 2);
  (void)ws_size; (void)n_in;

  hipMemsetAsync(bkt_cursor, 0, (size_t)NB * 4, stream);

  bucket_fill_kernel<<<CBLKS + 256, THREADS, 0, stream>>>(
      src, dst, bkt_cursor, edges_tmp, E, W_in, W1, W2, W3, Wtb);
  node_sort_kernel<<<NB, THREADS, 0, stream>>>(
      edges_tmp, bkt_cursor, batch, row_beg, deg, dis, csr_src, g_off,
      (unsigned*)hwb, N, G);

  int tileBlocks = (N + 31) / 32;
  int aggBlocks = (N + 3) / 4;

  const unsigned short* Wt0 = Wtb;
  const unsigned short* Wt1 = Wtb + 32768;
  const unsigned short* Wt2 = Wtb + 2 * 32768;
  const unsigned short* Wt3 = Wtb + 3 * 32768;

  // fused: h = x@W_in + b_in ; hwb = (h@W1)*dis
  gemm_in_kernel<<<tileBlocks, THREADS, 0, stream>>>(
      x, Wt0, b_in, Wt1, dis, h, hwb, N);
  agg_kernel<<<aggBlocks, THREADS, 0, stream>>>(h, hwb, b1, dis, row_beg, deg, csr_src, r1, N);
  gemm_mfma<0><<<tileBlocks, THREADS, 0, stream>>>(r1, Wt2, nullptr, dis, hwb, N);
  agg_kernel<<<aggBlocks, THREADS, 0, stream>>>(r1, hwb, b2, dis, row_beg, deg, csr_src, r2, N);
  gemm_mfma<0><<<tileBlocks, THREADS, 0, stream>>>(r2, Wt3, nullptr, dis, hwb, N);
  agg_kernel<<<aggBlocks, THREADS, 0, stream>>>(r2, hwb, b3, dis, row_beg, deg, csr_src, r3, N);

  pool_head_kernel<<<G, 512, 0, stream>>>(
      r1, r2, r3, g_off, Wp1, bp1, Wp2, bp2, out);
}